// Round 15
// baseline (196.363 us; speedup 1.0000x reference)
//
#include <hip/hip_runtime.h>
#include <math.h>

#define BATCH 32
#define HIN   224
#define WIN   224
#define CIN   3
#define KOUT  64
#define RK    5
#define HOUT  220
#define WOUT  220

#define STRIPS_Y  110               // 2 output rows per strip, 220 = 110*2 exact
#define NSTRIP    (STRIPS_Y * BATCH)  // 3520
#define NBLK      880               // x4 strips each, exactly balanced
#define ROWF      (WIN * CIN)       // 672 floats per input row
#define SROW_FL   (6 * ROWF)        // 4032 floats staged per strip
#define SROW_CH   (SROW_FL / 4)     // 1008 16B chunks
#define NTOT ((size_t)BATCH * HOUT * WOUT * KOUT)

typedef float  v4f    __attribute__((ext_vector_type(4)));
typedef short  short8 __attribute__((ext_vector_type(8)));   // 8 bf16 = 4 VGPRs

// d_ws: [0,12288) 768 x short8 weight frags | [12288,12544) 64 f32 softplus(w_sigma)
#define WS_WF_FRAGS 768
#define WS_WSG_OFF  12288

__device__ __forceinline__ float exp2_hw(float x) { float r; asm("v_exp_f32 %0, %1" : "=v"(r) : "v"(x)); return r; }
__device__ __forceinline__ float log2_hw(float x) { float r; asm("v_log_f32 %0, %1" : "=v"(r) : "v"(x)); return r; }
#define LOG2E 1.44269504088896f
#define LN2   0.69314718055995f

__device__ __forceinline__ float softplus_hw(float x) {       // general, stable
    float t = exp2_hw(-fabsf(x) * LOG2E);
    return fmaxf(x, 0.0f) + LN2 * log2_hw(1.0f + t);
}
__device__ __forceinline__ float softplus_pos(float y) {      // y >= 0 fast path
    return y + LN2 * log2_hw(1.0f + exp2_hw(-y * LOG2E));
}
__device__ __forceinline__ short f2bf(float x) {              // f32 -> bf16, RNE (prep only)
    unsigned u = __float_as_uint(x);
    u = (u + 0x7FFFu + ((u >> 16) & 1u)) >> 16;
    return (short)u;
}

// ---- prep: weight frags (bf16) + softplus(w_sigma) + KL ----
// A-frag (16x16x32, M=16 ch): row = lane&15, k = (lane>>4)*8 + i.
// k-order: k = kh*16 + (kw*3 + c); inner==15 and k>=80 are zero pads.
__global__ __launch_bounds__(256) void vdp_prep_kernel(
    const float* __restrict__ w_mu, const float* __restrict__ w_sigma,
    void* __restrict__ ws, float* __restrict__ out)
{
    __shared__ float red[4];
    short8* wf = (short8*)ws;
    float* wsg = (float*)((char*)ws + WS_WSG_OFF);
    const int t = threadIdx.x;

    for (int f = t; f < WS_WF_FRAGS; f += 256) {   // f = (s*4+nb)*64 + lane
        const int s  = f >> 8;
        const int nb = (f >> 6) & 3;
        const int l  = f & 63;
        const int ch = nb * 16 + (l & 15);
        const int h2 = l >> 4;
        short8 r;
        #pragma unroll
        for (int i = 0; i < 8; ++i) {
            const int k = s * 32 + h2 * 8 + i;
            const int kh = k >> 4, inner = k & 15;
            float v = 0.0f;
            if (inner < 15 && k < 80) {
                const int kw = inner / 3;
                const int c  = inner - kw * 3;
                v = w_mu[((kh * 5 + kw) * 3 + c) * KOUT + ch];
            }
            r[i] = f2bf(v);
        }
        wf[f] = r;
    }
    if (t < KOUT) wsg[t] = softplus_hw(w_sigma[t]);

    float s = 0.0f;
    for (int i = t; i < RK * RK * CIN * KOUT; i += 256) {
        const float v = w_mu[i];
        s = fmaf(v, v, s);
    }
    float u = s * (100.0f / 4800.0f);
    if (t < KOUT) {
        const float wsv = w_sigma[t];
        u += (-wsv + softplus_hw(wsv) * 100.0f) * (1.0f / 64.0f);
    }
    #pragma unroll
    for (int off = 32; off > 0; off >>= 1)
        u += __shfl_down(u, off, 64);
    if ((t & 63) == 0) red[t >> 6] = u;
    __syncthreads();
    if (t == 0) {
        const float U = red[0] + red[1] + red[2] + red[3];
        out[2 * NTOT] = 0.5f * (-4.6051701860f - 1.0f + U);
    }
}

// stage one strip: 6 full input rows = 16128 B CONTIGUOUS in global -> linear LDS
__device__ __forceinline__ void stage_strip(const float* __restrict__ mu_in, int t,
                                            float* buf, int tid)
{
    const int b  = t / STRIPS_Y;
    const int sy = t - b * STRIPS_Y;
    const float* gb = mu_in + ((size_t)b * HIN + sy * 2) * ROWF;
    #pragma unroll
    for (int it = 0; it < 4; ++it) {
        const int ci = it * 256 + (tid & ~63);       // wave-uniform chunk base
        if (ci < SROW_CH) {
            const int il = ci + (tid & 63);
            if (il < SROW_CH) {                      // exec-masks trailing lanes of last wave
                __builtin_amdgcn_global_load_lds(
                    (const __attribute__((address_space(1))) void*)(gb + il * 4),
                    (__attribute__((address_space(3))) void*)(buf + ci * 4),
                    16, 0, 0);
            }
        }
    }
}

// ---- conv: block = 4 consecutive strips of (2 rows x 220 px); wave = 1 row-half ----
__global__ __launch_bounds__(256, 4) void vdp_conv_kernel(
    const float* __restrict__ mu_in, const void* __restrict__ ws, float* __restrict__ out)
{
    __shared__ float s_row[2][SROW_FL];   // dbuf staged rows (32.25 KB)
    __shared__ float s_ssq[6][224];       // per-pixel sum_c x^2 (5.25 KB)
    __shared__ float s_cs[2][224];        // 5-row column sums  (1.75 KB)

    const int tid  = threadIdx.x;
    const int lane = tid & 63;
    const int wid  = tid >> 6;
    const int p    = lane & 15;           // MFMA: pixel-in-group; sigma: ch-group
    const int h2   = lane >> 4;           // MFMA: k subgroup;    sigma: px-in-quad
    const int rt   = wid & 1;             // output row within strip
    const int half = wid >> 1;            // pixel half: 0 -> px 0..111, 1 -> 112..219

    // XCD-aware bijective swizzle (880 = 8*110): neighbors share an XCD's L2
    const int bid = blockIdx.x;
    const int wg  = (bid & 7) * (NBLK / 8) + (bid >> 3);
    const int t0  = wg * 4;

    // weight frags (L2/L3-hot) + sigma scale
    const short8* wfg = (const short8*)ws;
    short8 wf[12];
    #pragma unroll
    for (int f = 0; f < 12; ++f) wf[f] = wfg[f * 64 + lane];
    const float* wsg_g = (const float*)((const char*)ws + WS_WSG_OFF);
    const v4f wsg_kg = *(const v4f*)(wsg_g + p * 4);

    stage_strip(mu_in, t0, s_row[0], tid);
    __syncthreads();                      // prologue: frags + strip 0 drained

    int cur = 0;
    #pragma unroll 1
    for (int k4 = 0; k4 < 4; ++k4) {
        const int t  = t0 + k4;
        const int b  = t / STRIPS_Y;
        const int sy = t - b * STRIPS_Y;
        const int r0 = sy * 2;

        // issue next strip's staging into the other buffer (hides under compute)
        if (k4 < 3) stage_strip(mu_in, t + 1, s_row[cur ^ 1], tid);
        __builtin_amdgcn_sched_barrier(0);

        const float* srow = s_row[cur];

        // per-pixel channel-summed squares (6 x 224)
        #pragma unroll
        for (int i = 0; i < 6; ++i) {
            const int idx = i * 256 + tid;
            if (idx < 6 * 224) {
                const int r = idx / 224, px = idx - r * 224;
                const float* q = srow + r * ROWF + 3 * px;
                s_ssq[r][px] = fmaf(q[0], q[0], fmaf(q[1], q[1], q[2] * q[2]));
            }
        }
        asm volatile("s_waitcnt lgkmcnt(0)" ::: "memory");
        __builtin_amdgcn_s_barrier();

        // column sums over 5 rows (2 x 224)
        #pragma unroll
        for (int i = 0; i < 2; ++i) {
            const int idx = i * 256 + tid;
            if (idx < 2 * 224) {
                const int rr = idx / 224, px = idx - rr * 224;
                s_cs[rr][px] = s_ssq[rr][px] + s_ssq[rr + 1][px] + s_ssq[rr + 2][px]
                             + s_ssq[rr + 3][px] + s_ssq[rr + 4][px];
            }
        }
        asm volatile("s_waitcnt lgkmcnt(0)" ::: "memory");
        __builtin_amdgcn_s_barrier();

        const size_t rowbase = ((size_t)b * HOUT + r0 + rt) * WOUT * KOUT;

        // ---- mu: 7 groups of 16 px, left->right sequential 4KB chunks ----
        #pragma unroll 1
        for (int g = 0; g < 7; ++g) {
            int wo = half ? 112 + 16 * g : 16 * g;
            if (wo > WOUT - 16) wo = WOUT - 16;      // only (half=1,g=6): 208->204 overlap

            short8 pf[3];
            #pragma unroll
            for (int s = 0; s < 3; ++s) {
                int ridx = rt + 2 * s + (h2 >> 1);
                ridx = ridx > 5 ? 5 : ridx;          // k>=80 pad slots: value x 0-weight
                const float* rp = srow + ridx * ROWF + 3 * (wo + p) + 8 * (h2 & 1);
                union { unsigned u[4]; short8 v; } cv;
                asm("v_cvt_pk_bf16_f32 %0, %1, %2" : "=v"(cv.u[0]) : "v"(rp[0]), "v"(rp[1]));
                asm("v_cvt_pk_bf16_f32 %0, %1, %2" : "=v"(cv.u[1]) : "v"(rp[2]), "v"(rp[3]));
                asm("v_cvt_pk_bf16_f32 %0, %1, %2" : "=v"(cv.u[2]) : "v"(rp[4]), "v"(rp[5]));
                asm("v_cvt_pk_bf16_f32 %0, %1, %2" : "=v"(cv.u[3]) : "v"(rp[6]), "v"(rp[7]));
                pf[s] = cv.v;
            }
            v4f acc[4];
            #pragma unroll
            for (int nb = 0; nb < 4; ++nb) {
                v4f a = {0.0f, 0.0f, 0.0f, 0.0f};
                #pragma unroll
                for (int s = 0; s < 3; ++s)
                    a = __builtin_amdgcn_mfma_f32_16x16x32_bf16(wf[s * 4 + nb], pf[s], a, 0, 0, 0);
                acc[nb] = a;
            }
            float* mp = out + rowbase + (size_t)(wo + p) * KOUT + h2 * 4;
            #pragma unroll
            for (int nb = 0; nb < 4; ++nb)
                *(v4f*)(mp + nb * 16) = acc[nb];
        }

        // ---- sigma: contiguous 1KB wave-stores, left->right (56KB/row total) ----
        {
            const int px0 = half * 112;
            const int nq  = half ? 27 : 28;          // 108 px vs 112 px
            float* sp = out + NTOT + rowbase + p * 4;
            #pragma unroll 1
            for (int q = 0; q < nq; ++q) {
                const int px = px0 + ((q << 2) | h2);
                const float sq = (s_cs[rt][px] + s_cs[rt][px + 1] + s_cs[rt][px + 2]
                                + s_cs[rt][px + 3] + s_cs[rt][px + 4]) * (1.0f / 75.0f);
                v4f sg;
                sg.x = softplus_pos(wsg_kg.x * sq);
                sg.y = softplus_pos(wsg_kg.y * sq);
                sg.z = softplus_pos(wsg_kg.z * sq);
                sg.w = softplus_pos(wsg_kg.w * sq);
                *(v4f*)(sp + (size_t)px * KOUT) = sg;
            }
        }

        // loop barrier: retire the 4 stage loads (oldest), keep stores in flight.
        // VMEM order/wave: [<=4 loads][~55 stores]; vmcnt(48) retires loads w/ margin.
        asm volatile("s_waitcnt vmcnt(48) lgkmcnt(0)" ::: "memory");
        __builtin_amdgcn_s_barrier();
        cur ^= 1;
    }
}

extern "C" void kernel_launch(void* const* d_in, const int* in_sizes, int n_in,
                              void* d_out, int out_size, void* d_ws, size_t ws_size,
                              hipStream_t stream)
{
    (void)in_sizes; (void)n_in; (void)ws_size; (void)out_size;
    const float* mu_in   = (const float*)d_in[0];
    const float* w_mu    = (const float*)d_in[1];
    const float* w_sigma = (const float*)d_in[2];
    float* out = (float*)d_out;

    vdp_prep_kernel<<<1, 256, 0, stream>>>(w_mu, w_sigma, d_ws, out);
    vdp_conv_kernel<<<NBLK, 256, 0, stream>>>(mu_in, d_ws, out);
}

// Round 16
// 171.951 us; speedup vs baseline: 1.1420x; 1.1420x over previous
//
#include <hip/hip_runtime.h>
#include <math.h>

#define BATCH 32
#define HIN   224
#define WIN   224
#define CIN   3
#define KOUT  64
#define RK    5
#define HOUT  220
#define WOUT  220

#define TS       16                 // tile: 16x16 output px
#define PATCH    20
#define NTOT ((size_t)BATCH * HOUT * WOUT * KOUT)

typedef float  v4f    __attribute__((ext_vector_type(4)));
typedef short  short8 __attribute__((ext_vector_type(8)));   // 8 bf16 = 4 VGPRs

// d_ws: [0,12288) 768 x short8 weight frags | [12288,12544) 64 f32 softplus(w_sigma)
#define WS_WF_FRAGS 768
#define WS_WSG_OFF  12288

__device__ __forceinline__ float exp2_hw(float x) { float r; asm("v_exp_f32 %0, %1" : "=v"(r) : "v"(x)); return r; }
__device__ __forceinline__ float log2_hw(float x) { float r; asm("v_log_f32 %0, %1" : "=v"(r) : "v"(x)); return r; }
#define LOG2E 1.44269504088896f
#define LN2   0.69314718055995f

__device__ __forceinline__ float softplus_hw(float x) {       // general, stable
    float t = exp2_hw(-fabsf(x) * LOG2E);
    return fmaxf(x, 0.0f) + LN2 * log2_hw(1.0f + t);
}
__device__ __forceinline__ float softplus_pos(float y) {      // y >= 0 fast path
    return y + LN2 * log2_hw(1.0f + exp2_hw(-y * LOG2E));
}
__device__ __forceinline__ short f2bf(float x) {              // f32 -> bf16, RNE (prep only)
    unsigned u = __float_as_uint(x);
    u = (u + 0x7FFFu + ((u >> 16) & 1u)) >> 16;
    return (short)u;
}

// ---- prep (4 blocks): weight frags (bf16) + softplus(w_sigma) + KL ----
// A-frag (16x16x32, M=16 ch): row = lane&15, k = (lane>>4)*8 + i.
// k-order: k = kh*16 + (kw*3 + c); inner==15 and k>=80 are zero pads.
__global__ __launch_bounds__(256) void vdp_prep_kernel(
    const float* __restrict__ w_mu, const float* __restrict__ w_sigma,
    void* __restrict__ ws, float* __restrict__ out)
{
    __shared__ float red[4];
    short8* wf = (short8*)ws;
    float* wsg = (float*)((char*)ws + WS_WSG_OFF);
    const int t = threadIdx.x;
    const int blk = blockIdx.x;

    if (blk < 3) {                         // frags: 3 blocks x 256
        const int f = blk * 256 + t;
        const int s  = f >> 8;
        const int nb = (f >> 6) & 3;
        const int l  = f & 63;
        const int ch = nb * 16 + (l & 15);
        const int h2 = l >> 4;
        short8 r;
        #pragma unroll
        for (int i = 0; i < 8; ++i) {
            const int k = s * 32 + h2 * 8 + i;
            const int kh = k >> 4, inner = k & 15;
            float v = 0.0f;
            if (inner < 15 && k < 80) {
                const int kw = inner / 3;
                const int c  = inner - kw * 3;
                v = w_mu[((kh * 5 + kw) * 3 + c) * KOUT + ch];
            }
            r[i] = f2bf(v);
        }
        wf[f] = r;
        return;
    }

    // block 3: sigma scales + KL
    if (t < KOUT) wsg[t] = softplus_hw(w_sigma[t]);

    float s = 0.0f;
    for (int i = t; i < RK * RK * CIN * KOUT; i += 256) {
        const float v = w_mu[i];
        s = fmaf(v, v, s);
    }
    float u = s * (100.0f / 4800.0f);
    if (t < KOUT) {
        const float wsv = w_sigma[t];
        u += (-wsv + softplus_hw(wsv) * 100.0f) * (1.0f / 64.0f);
    }
    #pragma unroll
    for (int off = 32; off > 0; off >>= 1)
        u += __shfl_down(u, off, 64);
    if ((t & 63) == 0) red[t >> 6] = u;
    __syncthreads();
    if (t == 0) {
        const float U = red[0] + red[1] + red[2] + red[3];
        out[2 * NTOT] = 0.5f * (-4.6051701860f - 1.0f + U);
    }
}

// ---- conv: one-shot tile blocks; 2 barriers BEFORE any store, none after ----
__global__ __launch_bounds__(256, 4) void vdp_conv_kernel(
    const float* __restrict__ mu_in, const void* __restrict__ ws, float* __restrict__ out)
{
    __shared__ float s_row[PATCH * 64];   // staged patch rows (5 KB), cols 60..63 dup
    __shared__ float s_ssq[PATCH][PATCH]; // per-pixel sum_c x^2 (1.6 KB)

    const int tid  = threadIdx.x;
    const int lane = tid & 63;
    const int wid  = tid >> 6;
    const int p    = lane & 15;           // MFMA: pixel col; sigma: ch-group kg
    const int h2   = lane >> 4;           // MFMA: k subgroup;  sigma: px quad

    const int b = blockIdx.z;
    int ho0 = blockIdx.y * TS; if (ho0 > HOUT - TS) ho0 = HOUT - TS;  // overlap recompute
    int wo0 = blockIdx.x * TS; if (wo0 > WOUT - TS) wo0 = WOUT - TS;

    // weight frags (L2/L3-hot, coalesced) + sigma scale
    const short8* wfg = (const short8*)ws;
    short8 wf[12];
    #pragma unroll
    for (int f = 0; f < 12; ++f) wf[f] = wfg[f * 64 + lane];
    const float* wsg_g = (const float*)((const char*)ws + WS_WSG_OFF);
    const v4f wsg_kg = *(const v4f*)(wsg_g + p * 4);

    // stage patch: 20 rows x 16 chunks of 16B (async, linear LDS dest)
    {
        const float* gb = mu_in + ((size_t)b * HIN + ho0) * (WIN * CIN) + wo0 * CIN;
        #pragma unroll
        for (int it = 0; it < 2; ++it) {
            const int ci = it * 256 + (tid & ~63);       // wave-uniform chunk base
            if (ci < 320) {
                const int il = ci + (tid & 63);
                const int r  = il >> 4;
                int cc = il & 15; if (cc > 14) cc = 14;  // pad chunk: dup data, zero-weight slots
                const float* g = gb + r * (WIN * CIN) + cc * 4;
                __builtin_amdgcn_global_load_lds(
                    (const __attribute__((address_space(1))) void*)g,
                    (__attribute__((address_space(3))) void*)(s_row + ci * 4),
                    16, 0, 0);
            }
        }
    }
    // barrier 1: staging drained. NO stores outstanding yet -> vmcnt(0) is cheap.
    asm volatile("s_waitcnt vmcnt(0) lgkmcnt(0)" ::: "memory");
    __builtin_amdgcn_s_barrier();

    // per-pixel channel-summed squares (20 x 20)
    for (int idx = tid; idx < PATCH * PATCH; idx += 256) {
        const int r = idx / PATCH;
        const int px = idx - r * PATCH;
        const float x0 = s_row[r * 64 + 3 * px], x1 = s_row[r * 64 + 3 * px + 1],
                    x2 = s_row[r * 64 + 3 * px + 2];
        s_ssq[r][px] = fmaf(x0, x0, fmaf(x1, x1, x2 * x2));
    }
    // barrier 2: LDS-only. Still zero stores outstanding.
    asm volatile("s_waitcnt lgkmcnt(0)" ::: "memory");
    __builtin_amdgcn_s_barrier();

    // ---- from here: waves fully independent, stores never fenced ----
    #pragma unroll 1
    for (int j = 0; j < 4; ++j) {
        const int rt = (wid << 2) | j;
        const size_t rowbase = (((size_t)b * HOUT + ho0 + rt) * WOUT + wo0) * KOUT;

        // B-frags from LDS (broadcast reads)
        short8 pf[3];
        #pragma unroll
        for (int s = 0; s < 3; ++s) {
            int ridx = rt + 2 * s + (h2 >> 1);
            ridx = ridx > PATCH - 1 ? PATCH - 1 : ridx;   // k>=80 pad: value x 0-weight
            const float* rp = s_row + ridx * 64 + 3 * p + 8 * (h2 & 1);
            union { unsigned u[4]; short8 v; } cv;
            asm("v_cvt_pk_bf16_f32 %0, %1, %2" : "=v"(cv.u[0]) : "v"(rp[0]), "v"(rp[1]));
            asm("v_cvt_pk_bf16_f32 %0, %1, %2" : "=v"(cv.u[1]) : "v"(rp[2]), "v"(rp[3]));
            asm("v_cvt_pk_bf16_f32 %0, %1, %2" : "=v"(cv.u[2]) : "v"(rp[4]), "v"(rp[5]));
            asm("v_cvt_pk_bf16_f32 %0, %1, %2" : "=v"(cv.u[3]) : "v"(rp[6]), "v"(rp[7]));
            pf[s] = cv.v;
        }

        v4f acc[4];
        #pragma unroll
        for (int nb = 0; nb < 4; ++nb) {
            v4f a = {0.0f, 0.0f, 0.0f, 0.0f};
            #pragma unroll
            for (int s = 0; s < 3; ++s)
                a = __builtin_amdgcn_mfma_f32_16x16x32_bf16(wf[s * 4 + nb], pf[s], a, 0, 0, 0);
            acc[nb] = a;
        }

        // mu: D col = pixel p, rows = 4 ch at nb*16 + h2*4 (sector-complete)
        float* mp = out + rowbase + (size_t)p * KOUT + h2 * 4;
        #pragma unroll
        for (int nb = 0; nb < 4; ++nb)
            *(v4f*)(mp + nb * 16) = acc[nb];

        // sigma: per-wave box sums (lanes 0..15), distribute via shuffle
        float sqv = 0.0f;
        if (lane < 16) {
            #pragma unroll
            for (int kh = 0; kh < RK; ++kh)
                #pragma unroll
                for (int kw = 0; kw < RK; ++kw)
                    sqv += s_ssq[rt + kh][p + kw];
            sqv *= (1.0f / 75.0f);
        }
        float* sp = out + NTOT + rowbase + p * 4;    // p = kg here
        #pragma unroll
        for (int pp = 0; pp < 4; ++pp) {
            const int px = (h2 << 2) | pp;
            const float sq = __shfl(sqv, px, 64);
            v4f sg;
            sg.x = softplus_pos(wsg_kg.x * sq);
            sg.y = softplus_pos(wsg_kg.y * sq);
            sg.z = softplus_pos(wsg_kg.z * sq);
            sg.w = softplus_pos(wsg_kg.w * sq);
            *(v4f*)(sp + (size_t)px * KOUT) = sg;
        }
    }
}

extern "C" void kernel_launch(void* const* d_in, const int* in_sizes, int n_in,
                              void* d_out, int out_size, void* d_ws, size_t ws_size,
                              hipStream_t stream)
{
    (void)in_sizes; (void)n_in; (void)ws_size; (void)out_size;
    const float* mu_in   = (const float*)d_in[0];
    const float* w_mu    = (const float*)d_in[1];
    const float* w_sigma = (const float*)d_in[2];
    float* out = (float*)d_out;

    vdp_prep_kernel<<<4, 256, 0, stream>>>(w_mu, w_sigma, d_ws, out);
    dim3 grid((WOUT + TS - 1) / TS, (HOUT + TS - 1) / TS, BATCH);  // 14 x 14 x 32 = 6272
    vdp_conv_kernel<<<grid, 256, 0, stream>>>(mu_in, d_ws, out);
}